// Round 1
// baseline (1592.279 us; speedup 1.0000x reference)
//
#include <hip/hip_runtime.h>

#define BB 64
#define TT 1024
#define CC 2
#define NN 128

// One workgroup per (b,c) chain: 128 blocks x 128 threads (2 waves).
// Thread j owns output tag j; holds E[i][j] = exp(trans[c][i][j]) in 128 VGPRs.
// Per step: p[i] = exp(alpha[i]-shift) shared via LDS, plain FMA matvec,
// alpha'[j] = shift + log(s_j) + emit[t][j]. shift = alpha[0] (broadcast).
__global__ __launch_bounds__(128, 1)
void crf_logz_kernel(const float* __restrict__ emissions,
                     const int* __restrict__ lengths,
                     const float* __restrict__ transitions,
                     const float* __restrict__ start_trans,
                     const float* __restrict__ end_trans,
                     float* __restrict__ out)
{
    const int bc = blockIdx.x;
    const int b  = bc >> 1;
    const int c  = bc & 1;
    const int j  = threadIdx.x;          // 0..127

    __shared__ float4 pvec[NN / 4];      // p[i] = exp(alpha[i] - shift)
    __shared__ float  a0_sh;             // broadcast slot for alpha[0]
    __shared__ float  red[NN];           // final reduction scratch

    // ---- one-time: E column for this thread's output tag ----
    float e[NN];
    #pragma unroll
    for (int i = 0; i < NN; ++i)
        e[i] = __expf(transitions[(c * NN + i) * NN + j]);

    const int len  = lengths[b];         // guaranteed in [T/2, T]
    const int tmax = len - 1;            // last t participating in the scan

    // emissions[b][t][c][j]; stride between consecutive t is C*N floats
    const float* emis = emissions + ((b * TT) * CC + c) * NN + j;

    float alpha = start_trans[c * NN + j] + emis[0];

    // 2-deep emission prefetch pipeline
    float ecur  = emis[min(1, tmax) * (CC * NN)];
    float enext = emis[min(2, tmax) * (CC * NN)];

    float* pp = (float*)pvec;

    for (int t = 1; t < len; ++t) {
        // issue prefetch of emit[t+2] early (clamped, always in-bounds)
        const int tp = (t + 2 <= tmax) ? (t + 2) : tmax;
        const float eload = emis[tp * (CC * NN)];

        // broadcast shift = alpha[0]
        if (j == 0) a0_sh = alpha;
        __syncthreads();                          // also: everyone done reading prev p
        const float shift = a0_sh;
        pp[j] = __expf(alpha - shift);            // |alpha - shift| bounded ~<=12
        __syncthreads();                          // p ready

        // matvec: s_j = sum_i p[i] * E[i][j]  (broadcast LDS reads, 4 accumulators)
        float s0 = 0.f, s1 = 0.f, s2 = 0.f, s3 = 0.f;
        #pragma unroll
        for (int i = 0; i < NN / 4; ++i) {
            const float4 pv = pvec[i];
            s0 = fmaf(pv.x, e[4 * i + 0], s0);
            s1 = fmaf(pv.y, e[4 * i + 1], s1);
            s2 = fmaf(pv.z, e[4 * i + 2], s2);
            s3 = fmaf(pv.w, e[4 * i + 3], s3);
        }
        const float s = (s0 + s1) + (s2 + s3);

        alpha = shift + __logf(s) + ecur;

        ecur  = enext;
        enext = eload;
    }

    // ---- final logsumexp over j of (alpha + end_trans[c][j]) ----
    red[j] = alpha + end_trans[c * NN + j];
    __syncthreads();
    if (j < 64) {
        const float x = red[j], y = red[j + 64];
        float m = fmaxf(x, y);
        #pragma unroll
        for (int off = 32; off > 0; off >>= 1)
            m = fmaxf(m, __shfl_xor(m, off));
        float s = __expf(x - m) + __expf(y - m);
        #pragma unroll
        for (int off = 32; off > 0; off >>= 1)
            s += __shfl_xor(s, off);
        if (j == 0) out[b * CC + c] = m + __logf(s);
    }
}

extern "C" void kernel_launch(void* const* d_in, const int* in_sizes, int n_in,
                              void* d_out, int out_size, void* d_ws, size_t ws_size,
                              hipStream_t stream) {
    const float* emissions   = (const float*)d_in[0];
    const int*   lengths     = (const int*)d_in[1];
    const float* transitions = (const float*)d_in[2];
    const float* start_t     = (const float*)d_in[3];
    const float* end_t       = (const float*)d_in[4];
    float* out = (float*)d_out;

    crf_logz_kernel<<<BB * CC, NN, 0, stream>>>(
        emissions, lengths, transitions, start_t, end_t, out);
}

// Round 2
// 746.531 us; speedup vs baseline: 2.1329x; 2.1329x over previous
//
#include <hip/hip_runtime.h>

#define BB 64
#define TT 1024
#define CC 2
#define NN 128

// Token-paste repetition for 32 float4 register-resident E-column chunks.
#define REP32(M) M(0)M(1)M(2)M(3)M(4)M(5)M(6)M(7)M(8)M(9)M(10)M(11)M(12)M(13)M(14)M(15)M(16)M(17)M(18)M(19)M(20)M(21)M(22)M(23)M(24)M(25)M(26)M(27)M(28)M(29)M(30)M(31)

// e##k = exp(trans[c][4k+0..3][j])  -- named float4 SSA values => guaranteed VGPRs
#define E_INIT(k) float4 e##k; \
    e##k.x = __expf(tr[(4*(k)+0)*NN + j]); \
    e##k.y = __expf(tr[(4*(k)+1)*NN + j]); \
    e##k.z = __expf(tr[(4*(k)+2)*NN + j]); \
    e##k.w = __expf(tr[(4*(k)+3)*NN + j]);

// s_j += p[4k..4k+3] . E[4k..4k+3][j]
#define MV(k) { const float4 pv = pcur[k]; \
    s0 = fmaf(pv.x, e##k.x, s0); s1 = fmaf(pv.y, e##k.y, s1); \
    s2 = fmaf(pv.z, e##k.z, s2); s3 = fmaf(pv.w, e##k.w, s3); }

// One scan step (phase Q in [1,3] of a 4-step group). Single barrier; stale shift.
#define DO_STEP(Q) { \
    const float p = __expf(alpha - shift); \
    pbufs[t & 1][j] = p; \
    if (j == 0) shbuf[t & 1] = alpha; \
    __syncthreads(); \
    const float nshift = shbuf[t & 1]; \
    const float em = etile[slot_r][(Q) * NN + j]; \
    const float4* __restrict__ pcur = (const float4*)pbufs[t & 1]; \
    float s0 = 0.f, s1 = 0.f, s2 = 0.f, s3 = 0.f; \
    REP32(MV) \
    alpha = shift + __logf((s0 + s1) + (s2 + s3)) + em; \
    shift = nshift; \
    ++t; }

// One workgroup (128 thr = 2 waves) per (b,c) chain. Thread j owns output tag j,
// holds E[*][j] = exp(trans) in 128 VGPRs. Per step: p=exp(alpha-shift) shared via
// double-buffered LDS (1 barrier), plain fp32 FMA matvec, log. shift is alpha[0]
// delayed one step (exact; only conditioning changes, bounded ~e^28 in fp32).
__global__ __launch_bounds__(128, 1)
void crf_logz_kernel(const float* __restrict__ emissions,
                     const int* __restrict__ lengths,
                     const float* __restrict__ transitions,
                     const float* __restrict__ start_trans,
                     const float* __restrict__ end_trans,
                     float* __restrict__ out)
{
    const int bc = blockIdx.x;
    const int b  = bc >> 1;
    const int c  = bc & 1;
    const int j  = threadIdx.x;            // 0..127

    __shared__ float pbufs[2][NN];         // double-buffered p = exp(alpha - shift)
    __shared__ float shbuf[2];             // double-buffered next-shift broadcast
    __shared__ float etile[3][4 * NN];     // emission tiles: 3 slots x 4 timesteps
    __shared__ float red[NN];              // final reduction scratch

    const float* tr = transitions + c * NN * NN;
    REP32(E_INIT)                          // 128 VGPRs of exp(trans), register-resident

    const int len  = lengths[b];           // in [T/2, T]
    const int tmax = len - 1;

    // emissions[b][t][c][*] base for this chain; t-stride = CC*NN floats
    const float* emisb = emissions + ((size_t)b * TT * CC + c) * NN;
    const int tagoff = (j & 31) * 4;       // float4 tag offset this thread stages
    const int qrow   = (j >> 5);           // which of 4 timesteps this thread stages

    // preload emission tiles for groups 0 (t=1..4) and 1 (t=5..8)
    #pragma unroll
    for (int g = 0; g < 2; ++g) {
        int tt = 1 + 4 * g + qrow; if (tt > tmax) tt = tmax;
        const float4 ev = *(const float4*)&emisb[(size_t)tt * (CC * NN) + tagoff];
        *(float4*)&etile[g][qrow * NN + tagoff] = ev;
    }

    float alpha = start_trans[c * NN + j] + emisb[j];   // t = 0
    float shift = 0.f;                     // valid first-step shift (|alpha|<~7)

    int t = 1;
    int slot_r = 0, slot_w = 2;
    while (t < len) {
        const int base = t;
        {   // ---- phase 0: also issues the group g+2 emission prefetch ----
            const float p = __expf(alpha - shift);
            pbufs[t & 1][j] = p;
            if (j == 0) shbuf[t & 1] = alpha;
            __syncthreads();
            const float nshift = shbuf[t & 1];
            // prefetch issued AFTER barrier: ~matvec-length of time to fly
            int tt = base + 8 + qrow; if (tt > tmax) tt = tmax;
            const float4 ev = *(const float4*)&emisb[(size_t)tt * (CC * NN) + tagoff];
            const float em = etile[slot_r][j];
            const float4* __restrict__ pcur = (const float4*)pbufs[t & 1];
            float s0 = 0.f, s1 = 0.f, s2 = 0.f, s3 = 0.f;
            REP32(MV)
            *(float4*)&etile[slot_w][qrow * NN + tagoff] = ev;  // lands post-matvec
            alpha = shift + __logf((s0 + s1) + (s2 + s3)) + em;
            shift = nshift;
            ++t;
        }
        if (t < len) DO_STEP(1)
        if (t < len) DO_STEP(2)
        if (t < len) DO_STEP(3)
        slot_r = (slot_r == 2) ? 0 : slot_r + 1;
        slot_w = (slot_w == 2) ? 0 : slot_w + 1;
    }

    // ---- final logsumexp over j of (alpha + end_trans[c][j]) ----
    red[j] = alpha + end_trans[c * NN + j];
    __syncthreads();
    if (j < 64) {
        const float x = red[j], y = red[j + 64];
        float m = fmaxf(x, y);
        #pragma unroll
        for (int off = 32; off > 0; off >>= 1)
            m = fmaxf(m, __shfl_xor(m, off));
        float s = __expf(x - m) + __expf(y - m);
        #pragma unroll
        for (int off = 32; off > 0; off >>= 1)
            s += __shfl_xor(s, off);
        if (j == 0) out[b * CC + c] = m + __logf(s);
    }
}

extern "C" void kernel_launch(void* const* d_in, const int* in_sizes, int n_in,
                              void* d_out, int out_size, void* d_ws, size_t ws_size,
                              hipStream_t stream) {
    const float* emissions   = (const float*)d_in[0];
    const int*   lengths     = (const int*)d_in[1];
    const float* transitions = (const float*)d_in[2];
    const float* start_t     = (const float*)d_in[3];
    const float* end_t       = (const float*)d_in[4];
    float* out = (float*)d_out;

    crf_logz_kernel<<<BB * CC, NN, 0, stream>>>(
        emissions, lengths, transitions, start_t, end_t, out);
}

// Round 3
// 649.119 us; speedup vs baseline: 2.4530x; 1.1501x over previous
//
#include <hip/hip_runtime.h>

#define BB 64
#define TT 1024
#define CC 2
#define NN 128
#define BS 256          // 4 waves: thread (j = tid&127, h = tid>>7)

#define REP16(M) M(0)M(1)M(2)M(3)M(4)M(5)M(6)M(7)M(8)M(9)M(10)M(11)M(12)M(13)M(14)M(15)

// e##k = exp(trans[c][ibase+4k+0..3][j]) -- 64 floats/thread, register-resident
#define E_INIT(k) float4 e##k; \
    e##k.x = __expf(tr[(ibase + 4*(k) + 0)*NN + j]); \
    e##k.y = __expf(tr[(ibase + 4*(k) + 1)*NN + j]); \
    e##k.z = __expf(tr[(ibase + 4*(k) + 2)*NN + j]); \
    e##k.w = __expf(tr[(ibase + 4*(k) + 3)*NN + j]);

#define MV(k) { const float4 pv = pc[k]; \
    s0 = fmaf(pv.x, e##k.x, s0); s1 = fmaf(pv.y, e##k.y, s1); \
    s2 = fmaf(pv.z, e##k.z, s2); s3 = fmaf(pv.w, e##k.w, s3); }

// One scan step, phase Q in [1,3] of a 4-step emission group.
#define DO_STEP(Q) { \
    if (lead) { pbufs[t & 1][j] = __expf(alpha - shift); \
                if (j == 0) shbuf[t & 1] = alpha; } \
    __syncthreads();                               /* bar A: p ready */ \
    const float nshift = shbuf[t & 1]; \
    float em = 0.f; if (lead) em = etile[slot_r][(Q) * NN + j]; \
    const float4* __restrict__ pc = (const float4*)&pbufs[t & 1][ibase]; \
    float s0 = 0.f, s1 = 0.f, s2 = 0.f, s3 = 0.f; \
    REP16(MV) \
    if (!lead) partial[j] = (s0 + s1) + (s2 + s3); \
    __syncthreads();                               /* bar B: partial ready */ \
    if (lead) { \
        const float s = ((s0 + s1) + (s2 + s3)) + partial[j]; \
        alpha = shift + __logf(s) + em; \
        shift = nshift; \
    } \
    ++t; }

// One workgroup (256 thr = 4 waves) per (b,c) chain. i-dimension split in two
// teams (h) so each thread's E-column half (64 floats) is register-resident —
// round 2's 128-float version spilled to scratch (VGPR_Count=96 < 128).
// shift = alpha[0] one step stale (exact; conditioning only, bounded ~e^28).
__global__ __launch_bounds__(BS, 1)
void crf_logz_kernel(const float* __restrict__ emissions,
                     const int* __restrict__ lengths,
                     const float* __restrict__ transitions,
                     const float* __restrict__ start_trans,
                     const float* __restrict__ end_trans,
                     float* __restrict__ out)
{
    const int bc = blockIdx.x;
    const int b  = bc >> 1;
    const int c  = bc & 1;
    const int tid = threadIdx.x;
    const int j    = tid & (NN - 1);       // output tag
    const int h    = tid >> 7;             // team: i in [64h, 64h+64)
    const int ibase = h << 6;
    const bool lead = (h == 0);

    __shared__ float pbufs[2][NN];         // double-buffered p = exp(alpha - shift)
    __shared__ float shbuf[2];             // double-buffered next-shift broadcast
    __shared__ float partial[NN];          // h=1 partial sums
    __shared__ float etile[3][4 * NN];     // emission tiles: 3 slots x 4 timesteps
    __shared__ float red[NN];              // final reduction scratch

    const float* tr = transitions + c * NN * NN;
    REP16(E_INIT)                          // 16 float4 = 64 VGPRs of exp(trans)

    const int len  = lengths[b];           // in [T/2, T]
    const int tmax = len - 1;

    // emissions[b][t][c][*] base; t-stride = CC*NN floats
    const float* emisb = emissions + ((size_t)b * TT * CC + c) * NN;
    const int tagoff = (tid & 63) * 2;     // float2 this thread stages
    const int qrow   = tid >> 6;           // which of 4 timesteps (0..3)

    // preload emission tiles for groups 0 (t=1..4) and 1 (t=5..8)
    #pragma unroll
    for (int g = 0; g < 2; ++g) {
        int tt = 1 + 4 * g + qrow; if (tt > tmax) tt = tmax;
        const float2 ev = *(const float2*)&emisb[(size_t)tt * (CC * NN) + tagoff];
        *(float2*)&etile[g][qrow * NN + tagoff] = ev;
    }

    float alpha = 0.f, shift = 0.f;
    if (lead) alpha = start_trans[c * NN + j] + emisb[j];   // t = 0

    int t = 1;
    int slot_r = 0, slot_w = 2;
    while (t < len) {
        const int base = t;
        {   // ---- phase 0: also stages the group g+2 emission tile ----
            if (lead) { pbufs[t & 1][j] = __expf(alpha - shift);
                        if (j == 0) shbuf[t & 1] = alpha; }
            __syncthreads();                           // bar A
            const float nshift = shbuf[t & 1];
            int tt = base + 8 + qrow; if (tt > tmax) tt = tmax;
            const float2 ev = *(const float2*)&emisb[(size_t)tt * (CC * NN) + tagoff];
            float em = 0.f; if (lead) em = etile[slot_r][j];
            const float4* __restrict__ pc = (const float4*)&pbufs[t & 1][ibase];
            float s0 = 0.f, s1 = 0.f, s2 = 0.f, s3 = 0.f;
            REP16(MV)
            *(float2*)&etile[slot_w][qrow * NN + tagoff] = ev;  // lands post-matvec
            if (!lead) partial[j] = (s0 + s1) + (s2 + s3);
            __syncthreads();                           // bar B
            if (lead) {
                const float s = ((s0 + s1) + (s2 + s3)) + partial[j];
                alpha = shift + __logf(s) + em;
                shift = nshift;
            }
            ++t;
        }
        if (t < len) DO_STEP(1)
        if (t < len) DO_STEP(2)
        if (t < len) DO_STEP(3)
        slot_r = (slot_r == 2) ? 0 : slot_r + 1;
        slot_w = (slot_w == 2) ? 0 : slot_w + 1;
    }

    // ---- final logsumexp over j of (alpha + end_trans[c][j]) ----
    if (lead) red[j] = alpha + end_trans[c * NN + j];
    __syncthreads();
    if (tid < 64) {
        const float x = red[tid], y = red[tid + 64];
        float m = fmaxf(x, y);
        #pragma unroll
        for (int off = 32; off > 0; off >>= 1)
            m = fmaxf(m, __shfl_xor(m, off));
        float s = __expf(x - m) + __expf(y - m);
        #pragma unroll
        for (int off = 32; off > 0; off >>= 1)
            s += __shfl_xor(s, off);
        if (tid == 0) out[b * CC + c] = m + __logf(s);
    }
}

extern "C" void kernel_launch(void* const* d_in, const int* in_sizes, int n_in,
                              void* d_out, int out_size, void* d_ws, size_t ws_size,
                              hipStream_t stream) {
    const float* emissions   = (const float*)d_in[0];
    const int*   lengths     = (const int*)d_in[1];
    const float* transitions = (const float*)d_in[2];
    const float* start_t     = (const float*)d_in[3];
    const float* end_t       = (const float*)d_in[4];
    float* out = (float*)d_out;

    crf_logz_kernel<<<BB * CC, BS, 0, stream>>>(
        emissions, lengths, transitions, start_t, end_t, out);
}